// Round 10
// baseline (1286.625 us; speedup 1.0000x reference)
//
#include <hip/hip_runtime.h>

// RecursiveEncoder on MI355X. B=16, H=256, S=16, C=5, L=6, N_LEAF=15625, N_INT=3906.
// R10: (1) leaf FUSED into level-5 (A-tile computed in-block into LDS; kills the
//      76us leaf kernel, a ~24us handoff, and 250MB of f6 HBM traffic);
//      (2) tail l3..l0+head: fence-free fused kernel — coherent (agent-scope
//      atomic) f32 stores/loads for inter-level data, barrier = vmcnt(0) +
//      relaxed RMW arrival + relaxed poll (R9's __threadfence = ~30us/barrier
//      L2 wb+inv across XCDs); register-direct GEMM (fine for tiny tiles).

#define B_ 16
#define H_ 256
#define NLEAF 15625
#define NINT 3906
#define TAILB 48

typedef __bf16 bf16_t;
typedef bf16_t bf16x8 __attribute__((ext_vector_type(8)));
typedef float f32x4 __attribute__((ext_vector_type(4)));

__device__ __forceinline__ void gl2lds16(const bf16_t* g, bf16_t* l) {
  __builtin_amdgcn_global_load_lds((const __attribute__((address_space(1))) void*)g,
                                   (__attribute__((address_space(3))) void*)l,
                                   16, 0, 0);
}

// =============== launch 1: prep (240 blocks) + bucket (245 blocks) ===========
__global__ __launch_bounds__(256) void front_kernel(
    const float* __restrict__ W_node, bf16_t* __restrict__ Wt,
    const int* __restrict__ node_type, int* __restrict__ counters,
    int2* __restrict__ buckets) {
  const int tid = threadIdx.x;
  const int bx = blockIdx.x;
  if (bx < 240) {
    const int t = bx / 80;
    const int kc = bx % 80;
    const float* srcp = W_node + (size_t)t * 1280 * 256 + tid;
    bf16_t* dstp = Wt + ((size_t)(t * 256 + tid)) * 1280;
#pragma unroll
    for (int k0 = kc * 16; k0 < kc * 16 + 16; k0 += 8) {
      bf16x8 v;
#pragma unroll
      for (int j = 0; j < 8; ++j) v[j] = (bf16_t)srcp[(size_t)(k0 + j) * 256];
      *(bf16x8*)(dstp + k0) = v;
    }
    return;
  }
  __shared__ int lcnt[18];
  __shared__ int lbase[18];
  if (tid < 18) lcnt[tid] = 0;
  __syncthreads();
  int idx = (bx - 240) * 256 + tid;
  bool active = idx < B_ * NINT;
  int t = 0, key = 0, mypos = 0;
  int2 e;
  int base = 0, nl_cap = 0;
  if (active) {
    int b = idx / NINT;
    int j = idx - b * NINT;
    int l, off;
    if (j >= 781)      { l = 5; off = 781; }
    else if (j >= 156) { l = 4; off = 156; }
    else if (j >= 31)  { l = 3; off = 31; }
    else if (j >= 6)   { l = 2; off = 6; }
    else if (j >= 1)   { l = 1; off = 1; }
    else               { l = 0; off = 0; }
    const int n_tab[6]    = {1, 5, 25, 125, 625, 3125};
    const int nn_tab[6]   = {5, 25, 125, 625, 3125, 15625};
    const int base_tab[6] = {0, 48, 288, 1488, 7488, 37488};
    int n_l = n_tab[l], nn = nn_tab[l];
    t = node_type[idx];
    int i = j - off;
    e.x = b * n_l + i;        // out row in level-l feature array
    e.y = b * nn + 5 * i;     // first child row in level-(l+1) feature array
    base = base_tab[l];
    nl_cap = B_ * n_l;
    key = l * 3 + t;
    mypos = atomicAdd(&lcnt[key], 1);
  }
  __syncthreads();
  if (tid < 18) {
    int c = lcnt[tid];
    lbase[tid] = c ? atomicAdd(&counters[tid], c) : 0;
  }
  __syncthreads();
  if (active) buckets[base + t * nl_cap + lbase[key] + mypos] = e;
}

// =============== launch 2: level-5 with fused leaf encoder ===================
// A-tile (128 rows x 1280 k) = 640 leaf encodings, computed in-block.
// Stage ks (64 k) == child cs=ks>>2, h-window hb=(ks&3)*64 — exact alignment.
// Thread computes h = hb*64+lane for rows r = wave+4k (wave-uniform inputs ->
// broadcast loads). Weights: 4 h-variants x 22 in regs. B: DMA dbuf (R5-proven).
__global__ __launch_bounds__(256, 2) void level5_fused_kernel(
    const float* __restrict__ leaf_box, const float* __restrict__ leaf_sem,
    const float* __restrict__ W_boxg, const float* __restrict__ b_boxg,
    const float* __restrict__ W_semg, const float* __restrict__ b_semg,
    bf16_t* __restrict__ dst, const int2* __restrict__ bucket,
    const int* __restrict__ counters, const bf16_t* __restrict__ Wt,
    const float* __restrict__ b_node, const float* __restrict__ ibox) {
  const int t = blockIdx.y;
  const int cnt = counters[15 + t];
  const int tile0 = blockIdx.x * 128;
  if (tile0 >= cnt) return;
  const int nblk = blockIdx.z;
  const int2* rd = bucket + 37488 + (size_t)t * (B_ * 3125);

  __shared__ __align__(16) bf16_t Asm[128 * 64];       // 16 KB single buffer
  __shared__ __align__(16) bf16_t Bsm[2 * 128 * 64];   // 32 KB dbuf
  __shared__ int rdy[128];

  const int tid = threadIdx.x;
  const int lane = tid & 63;
  const int wave = tid >> 6;
  const int wm = wave & 1, wn = wave >> 1;
  const int quad = lane >> 4;
  const int l15 = lane & 15;

  if (tid < 128) {
    int ai = tile0 + tid;
    if (ai >= cnt) ai = cnt - 1;
    rdy[tid] = rd[ai].y;  // first leaf row of this A-row
  }

  // leaf-encoder weights: wc[hb][0..3]=W_box col, [4..19]=W_sem col, [20]=b_box, [21]=b_sem
  float wc[4][22];
#pragma unroll
  for (int hb = 0; hb < 4; ++hb) {
    int h = hb * 64 + lane;
#pragma unroll
    for (int j = 0; j < 4; ++j) wc[hb][j] = W_boxg[j * H_ + h];
#pragma unroll
    for (int j = 0; j < 16; ++j) wc[hb][4 + j] = W_semg[j * H_ + h];
    wc[hb][20] = b_boxg[h];
    wc[hb][21] = b_semg[h];
  }

  // B staging ptrs
  const int r8 = tid >> 3;
  const int sc = tid & 7;
  const bf16_t* wsrc = Wt + ((size_t)t * 256 + nblk * 128) * 1280;
  const bf16_t* bptr[4];
#pragma unroll
  for (int i = 0; i < 4; ++i) {
    int r = i * 32 + r8;
    int gch = sc ^ ((r >> 1) & 7);
    bptr[i] = wsrc + (size_t)r * 1280 + gch * 8;
  }

  f32x4 acc[4][4];
#pragma unroll
  for (int i = 0; i < 4; ++i)
#pragma unroll
    for (int j = 0; j < 4; ++j) acc[i][j] = (f32x4){0.f, 0.f, 0.f, 0.f};

  const int sw = (l15 >> 1) & 7;
  const int pc0 = (quad ^ sw) * 8;
  const int pc1 = ((4 + quad) ^ sw) * 8;

#define STAGEB(buf, ks)                                           \
  {                                                               \
    bf16_t* lb = Bsm + (buf) * 8192 + wave * 512;                 \
    _Pragma("unroll") for (int i = 0; i < 4; ++i)                 \
        gl2lds16(bptr[i] + (ks) * 64, lb + i * 2048);             \
  }

#define CBODY(hb, cs)                                                          \
  {                                                                            \
    _Pragma("unroll 4") for (int k = 0; k < 32; ++k) {                         \
      int r = wave + 4 * k;                                                    \
      int lr = rdy[r] + (cs);                                                  \
      float4 bx = *(const float4*)(leaf_box + (size_t)lr * 4);                 \
      const float4* sp = (const float4*)(leaf_sem + (size_t)lr * 16);          \
      float4 s0 = sp[0], s1 = sp[1], s2 = sp[2], s3 = sp[3];                   \
      float a1 = fmaf(wc[hb][0], bx.x, fmaf(wc[hb][1], bx.y,                   \
                 fmaf(wc[hb][2], bx.z, fmaf(wc[hb][3], bx.w, wc[hb][20]))));   \
      float a2 = wc[hb][21];                                                   \
      a2 = fmaf(wc[hb][4], s0.x, a2);   a2 = fmaf(wc[hb][5], s0.y, a2);        \
      a2 = fmaf(wc[hb][6], s0.z, a2);   a2 = fmaf(wc[hb][7], s0.w, a2);        \
      a2 = fmaf(wc[hb][8], s1.x, a2);   a2 = fmaf(wc[hb][9], s1.y, a2);        \
      a2 = fmaf(wc[hb][10], s1.z, a2);  a2 = fmaf(wc[hb][11], s1.w, a2);       \
      a2 = fmaf(wc[hb][12], s2.x, a2);  a2 = fmaf(wc[hb][13], s2.y, a2);       \
      a2 = fmaf(wc[hb][14], s2.z, a2);  a2 = fmaf(wc[hb][15], s2.w, a2);       \
      a2 = fmaf(wc[hb][16], s3.x, a2);  a2 = fmaf(wc[hb][17], s3.y, a2);       \
      a2 = fmaf(wc[hb][18], s3.z, a2);  a2 = fmaf(wc[hb][19], s3.w, a2);       \
      bf16_t v = (bf16_t)(fmaxf(a1, 0.f) + fmaxf(a2, 0.f));                    \
      int slot = (lane >> 3) ^ ((r >> 1) & 7);                                 \
      Asm[r * 64 + slot * 8 + (lane & 7)] = v;                                 \
    }                                                                          \
  }

#define GSTAGE(hb, cs)                                                         \
  {                                                                            \
    const int ks = (cs) * 4 + (hb);                                            \
    const int buf = ks & 1;                                                    \
    CBODY(hb, cs)                                                              \
    __syncthreads(); /* A written; B[ks] DMA drained */                        \
    bf16x8 af0[4], af1[4], bf0[4], bf1[4];                                     \
    _Pragma("unroll") for (int am = 0; am < 4; ++am) {                         \
      const bf16_t* rp = Asm + (wm * 64 + am * 16 + l15) * 64;                 \
      af0[am] = *(const bf16x8*)(rp + pc0);                                    \
      af1[am] = *(const bf16x8*)(rp + pc1);                                    \
    }                                                                          \
    _Pragma("unroll") for (int bn = 0; bn < 4; ++bn) {                         \
      const bf16_t* rp = Bsm + buf * 8192 + (wn * 64 + bn * 16 + l15) * 64;    \
      bf0[bn] = *(const bf16x8*)(rp + pc0);                                    \
      bf1[bn] = *(const bf16x8*)(rp + pc1);                                    \
    }                                                                          \
    __syncthreads(); /* frags read; safe to overwrite A / reuse B buf */       \
    if (ks + 1 < 20) STAGEB(buf ^ 1, ks + 1)                                   \
    _Pragma("unroll") for (int am = 0; am < 4; ++am)                           \
        _Pragma("unroll") for (int bn = 0; bn < 4; ++bn)                       \
            acc[am][bn] = __builtin_amdgcn_mfma_f32_16x16x32_bf16(             \
                af0[am], bf0[bn], acc[am][bn], 0, 0, 0);                       \
    _Pragma("unroll") for (int am = 0; am < 4; ++am)                           \
        _Pragma("unroll") for (int bn = 0; bn < 4; ++bn)                       \
            acc[am][bn] = __builtin_amdgcn_mfma_f32_16x16x32_bf16(             \
                af1[am], bf1[bn], acc[am][bn], 0, 0, 0);                       \
  }

  STAGEB(0, 0)
#pragma unroll 1
  for (int cs = 0; cs < 5; ++cs) {
    GSTAGE(0, cs)
    GSTAGE(1, cs)
    GSTAGE(2, cs)
    GSTAGE(3, cs)
  }
#undef GSTAGE
#undef CBODY
#undef STAGEB

  // Epilogue (R5-proven). C/D: col = l15, row = quad*4 + reg.
  float wbv[4][6];
#pragma unroll
  for (int bn = 0; bn < 4; ++bn) {
    int col = nblk * 128 + wn * 64 + bn * 16 + l15;
    wbv[bn][0] = W_boxg[col];
    wbv[bn][1] = W_boxg[H_ + col];
    wbv[bn][2] = W_boxg[2 * H_ + col];
    wbv[bn][3] = W_boxg[3 * H_ + col];
    wbv[bn][4] = b_boxg[col];
    wbv[bn][5] = b_node[t * H_ + col];
  }
#pragma unroll
  for (int am = 0; am < 4; ++am) {
    int orow[4]; float4 bxv[4]; bool valid[4];
#pragma unroll
    for (int r = 0; r < 4; ++r) {
      int gidx = tile0 + wm * 64 + am * 16 + quad * 4 + r;
      valid[r] = (gidx < cnt);
      int ic = valid[r] ? gidx : (cnt - 1);
      int orw = rd[ic].x;
      orow[r] = orw;
      int b = orw / 3125;
      int i = orw - b * 3125;
      bxv[r] = *(const float4*)(ibox + ((size_t)b * NINT + 781 + i) * 4);
    }
#pragma unroll
    for (int bn = 0; bn < 4; ++bn) {
      int col = nblk * 128 + wn * 64 + bn * 16 + l15;
#pragma unroll
      for (int r = 0; r < 4; ++r) {
        if (!valid[r]) continue;
        float y = fmaxf(acc[am][bn][r] + wbv[bn][5], 0.f);
        float be = fmaf(wbv[bn][0], bxv[r].x,
                   fmaf(wbv[bn][1], bxv[r].y,
                   fmaf(wbv[bn][2], bxv[r].z,
                   fmaf(wbv[bn][3], bxv[r].w, wbv[bn][4]))));
        be = fmaxf(be, 0.f);
        dst[(size_t)orow[r] * H_ + col] = (bf16_t)(y + be);
      }
    }
  }
}

// =============== launch 3: level 4 (R5-proven LDS-DMA tile) ==================
__global__ __launch_bounds__(256) void level4_kernel(
    const bf16_t* __restrict__ src, bf16_t* __restrict__ dst,
    const int2* __restrict__ bucket, const int* __restrict__ counters,
    const bf16_t* __restrict__ Wt, const float* __restrict__ b_node,
    const float* __restrict__ ibox, const float* __restrict__ W_box,
    const float* __restrict__ b_box) {
  const int t = blockIdx.y;
  const int cnt = counters[12 + t];
  const int tile0 = blockIdx.x * 128;
  if (tile0 >= cnt) return;
  const int nblk = blockIdx.z;
  const int2* rd = bucket + 7488 + (size_t)t * (B_ * 625);

  __shared__ __align__(16) bf16_t Asm[2 * 128 * 64];
  __shared__ __align__(16) bf16_t Bsm[2 * 128 * 64];

  const int tid = threadIdx.x;
  const int lane = tid & 63;
  const int wave = tid >> 6;
  const int wm = wave & 1, wn = wave >> 1;
  const int quad = lane >> 4;
  const int l15 = lane & 15;

  const int r8 = tid >> 3;
  const int sc = tid & 7;
  const bf16_t* wsrc = Wt + ((size_t)t * 256 + nblk * 128) * 1280;
  const bf16_t* aptr[4];
  const bf16_t* bptr[4];
#pragma unroll
  for (int i = 0; i < 4; ++i) {
    int r = i * 32 + r8;
    int gch = sc ^ ((r >> 1) & 7);
    int ai = tile0 + r;
    if (ai >= cnt) ai = cnt - 1;
    aptr[i] = src + (size_t)rd[ai].y * H_ + gch * 8;
    bptr[i] = wsrc + (size_t)r * 1280 + gch * 8;
  }

  f32x4 acc[4][4];
#pragma unroll
  for (int i = 0; i < 4; ++i)
#pragma unroll
    for (int j = 0; j < 4; ++j) acc[i][j] = (f32x4){0.f, 0.f, 0.f, 0.f};

  const int sw = (l15 >> 1) & 7;
  const int pc0 = (quad ^ sw) * 8;
  const int pc1 = ((4 + quad) ^ sw) * 8;

#define STAGE(buf, ks)                                            \
  {                                                               \
    bf16_t* la = Asm + (buf) * 8192 + wave * 512;                 \
    bf16_t* lb = Bsm + (buf) * 8192 + wave * 512;                 \
    _Pragma("unroll") for (int i = 0; i < 4; ++i)                 \
        gl2lds16(aptr[i] + (ks) * 64, la + i * 2048);             \
    _Pragma("unroll") for (int i = 0; i < 4; ++i)                 \
        gl2lds16(bptr[i] + (ks) * 64, lb + i * 2048);             \
  }

  STAGE(0, 0)
  for (int ks = 0; ks < 20; ++ks) {
    const int buf = ks & 1;
    __syncthreads();
    bf16x8 af0[4], af1[4], bf0[4], bf1[4];
#pragma unroll
    for (int am = 0; am < 4; ++am) {
      const bf16_t* rp = Asm + buf * 8192 + (wm * 64 + am * 16 + l15) * 64;
      af0[am] = *(const bf16x8*)(rp + pc0);
      af1[am] = *(const bf16x8*)(rp + pc1);
    }
#pragma unroll
    for (int bn = 0; bn < 4; ++bn) {
      const bf16_t* rp = Bsm + buf * 8192 + (wn * 64 + bn * 16 + l15) * 64;
      bf0[bn] = *(const bf16x8*)(rp + pc0);
      bf1[bn] = *(const bf16x8*)(rp + pc1);
    }
    if (ks + 1 < 20) STAGE(buf ^ 1, ks + 1)
#pragma unroll
    for (int am = 0; am < 4; ++am)
#pragma unroll
      for (int bn = 0; bn < 4; ++bn)
        acc[am][bn] = __builtin_amdgcn_mfma_f32_16x16x32_bf16(af0[am], bf0[bn], acc[am][bn], 0, 0, 0);
#pragma unroll
    for (int am = 0; am < 4; ++am)
#pragma unroll
      for (int bn = 0; bn < 4; ++bn)
        acc[am][bn] = __builtin_amdgcn_mfma_f32_16x16x32_bf16(af1[am], bf1[bn], acc[am][bn], 0, 0, 0);
  }
#undef STAGE

  float wbv[4][6];
#pragma unroll
  for (int bn = 0; bn < 4; ++bn) {
    int col = nblk * 128 + wn * 64 + bn * 16 + l15;
    wbv[bn][0] = W_box[col];
    wbv[bn][1] = W_box[H_ + col];
    wbv[bn][2] = W_box[2 * H_ + col];
    wbv[bn][3] = W_box[3 * H_ + col];
    wbv[bn][4] = b_box[col];
    wbv[bn][5] = b_node[t * H_ + col];
  }
#pragma unroll
  for (int am = 0; am < 4; ++am) {
    int orow[4]; float4 bxv[4]; bool valid[4];
#pragma unroll
    for (int r = 0; r < 4; ++r) {
      int gidx = tile0 + wm * 64 + am * 16 + quad * 4 + r;
      valid[r] = (gidx < cnt);
      int ic = valid[r] ? gidx : (cnt - 1);
      int orw = rd[ic].x;
      orow[r] = orw;
      int b = orw / 625;
      int i = orw - b * 625;
      bxv[r] = *(const float4*)(ibox + ((size_t)b * NINT + 156 + i) * 4);
    }
#pragma unroll
    for (int bn = 0; bn < 4; ++bn) {
      int col = nblk * 128 + wn * 64 + bn * 16 + l15;
#pragma unroll
      for (int r = 0; r < 4; ++r) {
        if (!valid[r]) continue;
        float y = fmaxf(acc[am][bn][r] + wbv[bn][5], 0.f);
        float be = fmaf(wbv[bn][0], bxv[r].x,
                   fmaf(wbv[bn][1], bxv[r].y,
                   fmaf(wbv[bn][2], bxv[r].z,
                   fmaf(wbv[bn][3], bxv[r].w, wbv[bn][4]))));
        be = fmaxf(be, 0.f);
        dst[(size_t)orow[r] * H_ + col] = (bf16_t)(y + be);
      }
    }
  }
}

// =============== launch 4: tail = l3+l2+l1+l0+head, fence-free ===============
__device__ __forceinline__ bf16x8 cohA_f32(const float* p) {
  union { unsigned long long u[4]; float f[8]; } x;
#pragma unroll
  for (int i = 0; i < 4; ++i)
    x.u[i] = __hip_atomic_load(((const unsigned long long*)p) + i,
                               __ATOMIC_RELAXED, __HIP_MEMORY_SCOPE_AGENT);
  bf16x8 r;
#pragma unroll
  for (int i = 0; i < 8; ++i) r[i] = (bf16_t)x.f[i];
  return r;
}

// Register-direct 128x128 tile, K=1280 in 40 steps of 32. ACOH: A is f32 via
// coherent loads; else A is bf16 via normal loads. Output: coherent f32 stores.
template <bool ACOH>
__device__ __forceinline__ void tail_tile(
    const void* Ain, float* Aout, const int2* rd, int cnt,
    const bf16_t* __restrict__ Wt, const float* __restrict__ b_node,
    const float* __restrict__ ibox, const float* __restrict__ W_box,
    const float* __restrict__ b_box, int t, int n_l, int off_l, int tile0, int nblk) {
  const int tid = threadIdx.x;
  const int lane = tid & 63;
  const int wave = tid >> 6;
  const int wm = wave & 1, wn = wave >> 1;
  const int quad = lane >> 4;
  const int l15 = lane & 15;

  const bf16_t* ab[4];
  const float* af[4];
#pragma unroll
  for (int am = 0; am < 4; ++am) {
    int gidx = tile0 + wm * 64 + am * 16 + l15;
    if (gidx >= cnt) gidx = cnt - 1;
    size_t ro = (size_t)rd[gidx].y * H_ + quad * 8;
    ab[am] = (const bf16_t*)Ain + ro;
    af[am] = (const float*)Ain + ro;
  }
  const bf16_t* bb[4];
#pragma unroll
  for (int bn = 0; bn < 4; ++bn) {
    int col = nblk * 128 + wn * 64 + bn * 16 + l15;
    bb[bn] = Wt + ((size_t)t * 256 + col) * 1280 + quad * 8;
  }

  f32x4 acc[4][4];
#pragma unroll
  for (int i = 0; i < 4; ++i)
#pragma unroll
    for (int j = 0; j < 4; ++j) acc[i][j] = (f32x4){0.f, 0.f, 0.f, 0.f};

  bf16x8 A[2][4], Bv[2][4];

#define LOADF(buf, ks)                                                 \
  {                                                                    \
    const int ko = (ks) * 32;                                          \
    _Pragma("unroll") for (int i = 0; i < 4; ++i) {                    \
      if (ACOH) A[buf][i] = cohA_f32(af[i] + ko);                      \
      else      A[buf][i] = *(const bf16x8*)(ab[i] + ko);              \
      Bv[buf][i] = *(const bf16x8*)(bb[i] + ko);                       \
    }                                                                  \
  }
#define MFMAS(buf)                                                             \
  {                                                                            \
    _Pragma("unroll") for (int am = 0; am < 4; ++am)                           \
        _Pragma("unroll") for (int bn = 0; bn < 4; ++bn)                       \
            acc[am][bn] = __builtin_amdgcn_mfma_f32_16x16x32_bf16(             \
                A[buf][am], Bv[buf][bn], acc[am][bn], 0, 0, 0);                \
  }

  LOADF(0, 0)
  LOADF(1, 1)
  for (int ks = 0; ks < 40; ks += 2) {
    MFMAS(0)
    if (ks + 2 < 40) LOADF(0, ks + 2)
    MFMAS(1)
    if (ks + 3 < 40) LOADF(1, ks + 3)
  }
#undef LOADF
#undef MFMAS

  float wbv[4][6];
#pragma unroll
  for (int bn = 0; bn < 4; ++bn) {
    int col = nblk * 128 + wn * 64 + bn * 16 + l15;
    wbv[bn][0] = W_box[col];
    wbv[bn][1] = W_box[H_ + col];
    wbv[bn][2] = W_box[2 * H_ + col];
    wbv[bn][3] = W_box[3 * H_ + col];
    wbv[bn][4] = b_box[col];
    wbv[bn][5] = b_node[t * H_ + col];
  }
#pragma unroll
  for (int am = 0; am < 4; ++am) {
    int orow[4]; float4 bxv[4]; bool valid[4];
#pragma unroll
    for (int r = 0; r < 4; ++r) {
      int gidx = tile0 + wm * 64 + am * 16 + quad * 4 + r;
      valid[r] = (gidx < cnt);
      int ic = valid[r] ? gidx : (cnt - 1);
      int orw = rd[ic].x;
      orow[r] = orw;
      int b = orw / n_l;
      int i = orw - b * n_l;
      bxv[r] = *(const float4*)(ibox + ((size_t)b * NINT + off_l + i) * 4);
    }
#pragma unroll
    for (int bn = 0; bn < 4; ++bn) {
      int col = nblk * 128 + wn * 64 + bn * 16 + l15;
#pragma unroll
      for (int r = 0; r < 4; ++r) {
        if (!valid[r]) continue;
        float y = fmaxf(acc[am][bn][r] + wbv[bn][5], 0.f);
        float be = fmaf(wbv[bn][0], bxv[r].x,
                   fmaf(wbv[bn][1], bxv[r].y,
                   fmaf(wbv[bn][2], bxv[r].z,
                   fmaf(wbv[bn][3], bxv[r].w, wbv[bn][4]))));
        be = fmaxf(be, 0.f);
        __hip_atomic_store(&Aout[(size_t)orow[r] * H_ + col], y + be,
                           __ATOMIC_RELAXED, __HIP_MEMORY_SCOPE_AGENT);
      }
    }
  }
}

template <bool ACOH>
__device__ __forceinline__ void run_level(
    const void* fin, float* fout, const int2* bks, const int* cnts3,
    const bf16_t* Wt, const float* b_node, const float* ibox,
    const float* W_box, const float* b_box, int n_l, int off_l) {
  const int c0 = cnts3[0], c1 = cnts3[1], c2 = cnts3[2];
  const int T0 = (c0 + 127) >> 7, T1 = (c1 + 127) >> 7, T2 = (c2 + 127) >> 7;
  const int W = 2 * (T0 + T1 + T2);
  const int cap = B_ * n_l;
#pragma unroll 1
  for (int w = blockIdx.x; w < W; w += TAILB) {
    int nblk = w & 1, q = w >> 1;
    int t, tile, cnt;
    if (q < T0)           { t = 0; tile = q;           cnt = c0; }
    else if (q < T0 + T1) { t = 1; tile = q - T0;      cnt = c1; }
    else                  { t = 2; tile = q - T0 - T1; cnt = c2; }
    tail_tile<ACOH>(fin, fout, bks + (size_t)t * cap, cnt, Wt, b_node,
                    ibox, W_box, b_box, t, n_l, off_l, tile * 128, nblk);
  }
}

// Fence-free barrier: drain own coherent stores (vmcnt), count arrivals with
// relaxed agent RMW, poll with relaxed agent load. Data flows via coherent ops.
__device__ __forceinline__ void gbar(int* ctr) {
  asm volatile("s_waitcnt vmcnt(0)" ::: "memory");
  __syncthreads();
  if (threadIdx.x == 0) {
    __hip_atomic_fetch_add(ctr, 1, __ATOMIC_RELAXED, __HIP_MEMORY_SCOPE_AGENT);
    while (__hip_atomic_load(ctr, __ATOMIC_RELAXED, __HIP_MEMORY_SCOPE_AGENT) < TAILB)
      __builtin_amdgcn_s_sleep(8);
  }
  __syncthreads();
}

__global__ __launch_bounds__(256) void tail_kernel(
    const bf16_t* __restrict__ f4, float* __restrict__ g3,
    float* __restrict__ g2, float* __restrict__ g1, float* __restrict__ g0,
    const int2* __restrict__ buckets, const int* __restrict__ counters,
    int* __restrict__ bars,
    const bf16_t* __restrict__ Wt, const float* __restrict__ b_node,
    const float* __restrict__ ibox, const float* __restrict__ W_box,
    const float* __restrict__ b_box,
    const float* __restrict__ eps, const float* __restrict__ W1,
    const float* __restrict__ b1, const float* __restrict__ Wmu,
    const float* __restrict__ bmu, const float* __restrict__ Wvar,
    const float* __restrict__ bvar, float* __restrict__ out) {
  // l3: f4(bf16, from launch boundary -> normal loads) -> g3 (coherent f32)
  run_level<false>(f4, g3, buckets + 1488, counters + 9, Wt, b_node, ibox,
                   W_box, b_box, 125, 31);
  gbar(bars + 0);
  run_level<true>(g3, g2, buckets + 288, counters + 6, Wt, b_node, ibox,
                  W_box, b_box, 25, 6);
  gbar(bars + 1);
  run_level<true>(g2, g1, buckets + 48, counters + 3, Wt, b_node, ibox,
                  W_box, b_box, 5, 1);
  gbar(bars + 2);
  run_level<true>(g1, g0, buckets + 0, counters + 0, Wt, b_node, ibox,
                  W_box, b_box, 1, 0);
  gbar(bars + 3);

  if (blockIdx.x >= B_) return;
  __shared__ float root[256];
  __shared__ float enc[256];
  int b = blockIdx.x, h = threadIdx.x;
  root[h] = __hip_atomic_load(&g0[b * H_ + h], __ATOMIC_RELAXED,
                              __HIP_MEMORY_SCOPE_AGENT);
  __syncthreads();
  float a = b1[h];
#pragma unroll 8
  for (int k = 0; k < 256; ++k) a = fmaf(root[k], W1[k * H_ + h], a);
  enc[h] = fmaxf(a, 0.f);
  __syncthreads();
  float m = bmu[h], lv = bvar[h];
#pragma unroll 8
  for (int k = 0; k < 256; ++k) {
    float e = enc[k];
    m = fmaf(e, Wmu[k * H_ + h], m);
    lv = fmaf(e, Wvar[k * H_ + h], lv);
  }
  float stdv = expf(0.5f * lv);
  float kld = 1.f + lv - m * m - expf(lv);
  out[b * 512 + h] = eps[b * H_ + h] * stdv + m;
  out[b * 512 + 256 + h] = kld;
}

extern "C" void kernel_launch(void* const* d_in, const int* in_sizes, int n_in,
                              void* d_out, int out_size, void* d_ws, size_t ws_size,
                              hipStream_t stream) {
  const float* leaf_box     = (const float*)d_in[0];
  const float* leaf_sem     = (const float*)d_in[1];
  const float* internal_box = (const float*)d_in[2];
  const int*   node_type    = (const int*)d_in[3];
  const float* eps          = (const float*)d_in[4];
  const float* W_box        = (const float*)d_in[5];
  const float* b_box        = (const float*)d_in[6];
  const float* W_sem        = (const float*)d_in[7];
  const float* b_sem        = (const float*)d_in[8];
  const float* W_node       = (const float*)d_in[9];
  const float* b_node       = (const float*)d_in[10];
  const float* W1           = (const float*)d_in[11];
  const float* b1           = (const float*)d_in[12];
  const float* Wmu          = (const float*)d_in[13];
  const float* bmu          = (const float*)d_in[14];
  const float* Wvar         = (const float*)d_in[15];
  const float* bvar         = (const float*)d_in[16];
  float* out = (float*)d_out;

  char* p = (char*)d_ws;
  auto alloc = [&](size_t bytes) {
    char* r = p;
    p += (bytes + 255) & ~(size_t)255;
    return r;
  };
  bf16_t* Wt = (bf16_t*)alloc((size_t)3 * 256 * 1280 * 2);
  bf16_t* f5 = (bf16_t*)alloc((size_t)B_ * 3125 * H_ * 2);
  bf16_t* f4 = (bf16_t*)alloc((size_t)B_ * 625 * H_ * 2);
  float* g3 = (float*)alloc((size_t)B_ * 125 * H_ * 4);
  float* g2 = (float*)alloc((size_t)B_ * 25 * H_ * 4);
  float* g1 = (float*)alloc((size_t)B_ * 5 * H_ * 4);
  float* g0 = (float*)alloc((size_t)B_ * 1 * H_ * 4);
  int* counters = (int*)alloc(24 * 4);  // 18 bucket counters + 4 barrier slots
  int* bars = counters + 18;
  int2* buckets = (int2*)alloc((size_t)187488 * 8);

  hipMemsetAsync(counters, 0, 24 * 4, stream);
  hipLaunchKernelGGL(front_kernel, dim3(485), dim3(256), 0, stream,
                     W_node, Wt, node_type, counters, buckets);
  hipLaunchKernelGGL(level5_fused_kernel, dim3(391, 3, 2), dim3(256), 0, stream,
                     leaf_box, leaf_sem, W_box, b_box, W_sem, b_sem,
                     f5, buckets, counters, Wt, b_node, internal_box);
  hipLaunchKernelGGL(level4_kernel, dim3(79, 3, 2), dim3(256), 0, stream,
                     f5, f4, buckets, counters, Wt, b_node,
                     internal_box, W_box, b_box);
  hipLaunchKernelGGL(tail_kernel, dim3(TAILB), dim3(256), 0, stream,
                     f4, g3, g2, g1, g0, buckets, counters, bars,
                     Wt, b_node, internal_box, W_box, b_box,
                     eps, W1, b1, Wmu, bmu, Wvar, bvar, out);
}